// Round 2
// baseline (938.246 us; speedup 1.0000x reference)
//
#include <hip/hip_runtime.h>

#define DIM   64
#define NEMB  1024
#define HW    4096      // 64*64
#define NPIX  131072    // 32*64*64
#define NOUT  8388608   // 32*64*64*64
#define CPS   256       // codes per split (4 splits = 4 waves per block)

// ---------------------------------------------------------------------------
// prep: eT[j][d] = embed[d][j]  (transpose so code rows are contiguous for
// scalar loads), and cn[j] = sum_d embed[d][j]^2 computed with numpy's
// axis-0 semantics (separate rounded muls, sequential adds).
// ---------------------------------------------------------------------------
__global__ __launch_bounds__(256) void prep_kernel(const float* __restrict__ embed,
                                                   float* __restrict__ eT,
                                                   float* __restrict__ cn) {
    const int j = blockIdx.x * 256 + threadIdx.x;
    if (j >= NEMB) return;
    float v[DIM];
#pragma unroll
    for (int d = 0; d < DIM; ++d) {
        v[d] = embed[d * NEMB + j];      // coalesced across lanes (consecutive j)
        eT[j * DIM + d] = v[d];
    }
    float s = __fmul_rn(v[0], v[0]);
#pragma unroll
    for (int d = 1; d < DIM; ++d)
        s = __fadd_rn(s, __fmul_rn(v[d], v[d]));   // sequential, no contraction
    cn[j] = s;
}

// ---------------------------------------------------------------------------
// main: block = 64 pixels x 4 code-splits (one split per wave).
//   wave w scans codes [w*256, w*256+256) for the block's 64 pixels,
//   LDS packed-u64 min merges the 4 splits (dist>0 so float bits order;
//   idx in low bits -> exact ties pick the smaller index = np.argmin).
//   Epilogue: wave w writes d-planes [16w,16w+16) for all 64 pixels.
// Distance arithmetic is identical to the R0-passing version.
// ---------------------------------------------------------------------------
__global__ __launch_bounds__(256) void vq_kernel(const float* __restrict__ X,
                                                 const float* __restrict__ embed,
                                                 const float* __restrict__ eT,
                                                 const float* __restrict__ cn,
                                                 float* __restrict__ OUT,
                                                 float* __restrict__ loss) {
    const int tid   = threadIdx.x;
    const int split = tid >> 6;          // 0..3, wave-uniform
    const int q     = tid & 63;          // pixel slot within block
    const int pix   = blockIdx.x * 64 + q;
    const int b     = pix >> 12;         // image index (64 | 4096 so same b per block)
    const int p     = pix & 4095;        // h*64+w within image
    const float* xb = X + (size_t)b * (DIM * HW) + p;

    float x[DIM];
#pragma unroll
    for (int d = 0; d < DIM; ++d) x[d] = xb[(size_t)d * HW];   // coalesced per d

    // ||f||^2 with numpy pairwise 8-accumulator pattern (n=64, no tail)
    float r[8];
#pragma unroll
    for (int k = 0; k < 8; ++k) r[k] = __fmul_rn(x[k], x[k]);
#pragma unroll
    for (int i = 8; i < DIM; i += 8)
#pragma unroll
        for (int k = 0; k < 8; ++k)
            r[k] = __fadd_rn(r[k], __fmul_rn(x[i + k], x[i + k]));
    const float ff = __fadd_rn(
        __fadd_rn(__fadd_rn(r[0], r[1]), __fadd_rn(r[2], r[3])),
        __fadd_rn(__fadd_rn(r[4], r[5]), __fadd_rn(r[6], r[7])));

    float minv = __builtin_inff();
    int   mini = 0;
    const int jbase = split * CPS;

#pragma unroll 1
    for (int jj = 0; jj < CPS; jj += 4) {
        const int j0 = jbase + jj;
        const float* e = eT + (size_t)j0 * DIM;   // wave-uniform address -> s_load
        float a0 = 0.f, a1 = 0.f, a2 = 0.f, a3 = 0.f;
#pragma unroll
        for (int d = 0; d < DIM; ++d) {
            const float xd = x[d];
            a0 = fmaf(xd, e[d],           a0);   // sequential-k FMA (BLAS order)
            a1 = fmaf(xd, e[DIM + d],     a1);
            a2 = fmaf(xd, e[2 * DIM + d], a2);
            a3 = fmaf(xd, e[3 * DIM + d], a3);
        }
        const float d0 = __fadd_rn(__fsub_rn(ff, __fmul_rn(2.f, a0)), cn[j0 + 0]);
        const float d1 = __fadd_rn(__fsub_rn(ff, __fmul_rn(2.f, a1)), cn[j0 + 1]);
        const float d2 = __fadd_rn(__fsub_rn(ff, __fmul_rn(2.f, a2)), cn[j0 + 2]);
        const float d3 = __fadd_rn(__fsub_rn(ff, __fmul_rn(2.f, a3)), cn[j0 + 3]);
        if (d0 < minv) { minv = d0; mini = j0 + 0; }
        if (d1 < minv) { minv = d1; mini = j0 + 1; }
        if (d2 < minv) { minv = d2; mini = j0 + 2; }
        if (d3 < minv) { minv = d3; mini = j0 + 3; }
    }

    // merge the 4 splits per pixel via packed (float_bits<<32 | idx) min
    __shared__ unsigned long long sm[256];
    sm[tid] = ((unsigned long long)__float_as_uint(minv) << 32) | (unsigned)mini;
    __syncthreads();
    unsigned long long m01 = min(sm[q],       sm[64 + q]);
    unsigned long long m23 = min(sm[128 + q], sm[192 + q]);
    const int idx = (int)(min(m01, m23) & 0xFFFFFFFFull);

    // epilogue: wave `split` handles d in [16*split, 16*split+16) for pixel q
    float lerr = 0.f;
    float* outb = OUT + (size_t)b * (DIM * HW) + p;
#pragma unroll
    for (int k = 0; k < 16; ++k) {
        const int d = split * 16 + k;
        const float qv = embed[d * NEMB + idx];   // L2-resident gather (256 KB)
        const float xv = xb[(size_t)d * HW];      // L1/L2 hit (just read above)
        const float df = __fsub_rn(qv, xv);
        outb[(size_t)d * HW] = __fadd_rn(xv, df); // coalesced: lanes = consecutive p
        lerr = fmaf(df, df, lerr);
    }

    __shared__ float sred[256];
    sred[tid] = lerr;
    __syncthreads();
#pragma unroll
    for (int s = 128; s > 0; s >>= 1) {
        if (tid < s) sred[tid] += sred[tid + s];
        __syncthreads();
    }
    if (tid == 0)
        atomicAdd(loss, sred[0] * (1.0f / (float)NOUT));
}

extern "C" void kernel_launch(void* const* d_in, const int* in_sizes, int n_in,
                              void* d_out, int out_size, void* d_ws, size_t ws_size,
                              hipStream_t stream) {
    const float* X = (const float*)d_in[0];
    const float* E = (const float*)d_in[1];
    float* eT  = (float*)d_ws;                 // 1024*64 floats
    float* cn  = eT + NEMB * DIM;              // 1024 floats
    float* OUT = (float*)d_out;
    float* loss = OUT + NOUT;                  // second output (scalar)

    hipMemsetAsync(loss, 0, sizeof(float), stream);   // atomic accumulator
    prep_kernel<<<NEMB / 256, 256, 0, stream>>>(E, eT, cn);
    vq_kernel<<<NPIX / 64, 256, 0, stream>>>(X, E, eT, cn, OUT, loss);
}

// Round 3
// 340.634 us; speedup vs baseline: 2.7544x; 2.7544x over previous
//
#include <hip/hip_runtime.h>

#define DIM    64
#define NEMB   1024
#define HW     4096      // 64*64
#define NPIX   131072    // 32*64*64
#define NOUT   8388608   // 32*64*64*64
#define NSPLIT 4
#define CPS    (NEMB / NSPLIT)   // 256 codes per split

// ---------------------------------------------------------------------------
// prep: eT[j][d] = embed[d][j]  (code rows contiguous -> scalar s_load path),
// cn[j] = ||e_j||^2 with numpy axis-0 semantics (rounded muls, sequential adds)
// ---------------------------------------------------------------------------
__global__ __launch_bounds__(256) void prep_kernel(const float* __restrict__ embed,
                                                   float* __restrict__ eT,
                                                   float* __restrict__ cn) {
    const int j = blockIdx.x * 256 + threadIdx.x;
    if (j >= NEMB) return;
    float v[DIM];
#pragma unroll
    for (int d = 0; d < DIM; ++d) {
        v[d] = embed[d * NEMB + j];
        eT[j * DIM + d] = v[d];
    }
    float s = __fmul_rn(v[0], v[0]);
#pragma unroll
    for (int d = 1; d < DIM; ++d)
        s = __fadd_rn(s, __fmul_rn(v[d], v[d]));
    cn[j] = s;
}

// ---------------------------------------------------------------------------
// scan: block = 256 pixels, blockIdx.y = code split. The j-loop is
// BLOCK-uniform -> e rows go through the scalar (s_load/SGPR) pipe.
// __launch_bounds__(256,3) keeps x[64] in VGPRs (no spill).
// Arithmetic identical to the R0-passing kernel. Result: packed
// (dist_bits<<32 | idx) so u64-min = (min dist, first-occurrence tie).
// ---------------------------------------------------------------------------
__global__ __launch_bounds__(256, 3) void scan_kernel(const float* __restrict__ X,
                                                      const float* __restrict__ eT,
                                                      const float* __restrict__ cn,
                                                      unsigned long long* __restrict__ cand) {
    const int tid = threadIdx.x;
    const int pix = blockIdx.x * 256 + tid;
    const int b   = pix >> 12;
    const int p   = pix & 4095;
    const float* xb = X + (size_t)b * (DIM * HW) + p;

    float x[DIM];
#pragma unroll
    for (int d = 0; d < DIM; ++d) x[d] = xb[(size_t)d * HW];   // coalesced per d

    // ||f||^2, numpy pairwise 8-accumulator pattern (n=64)
    float r[8];
#pragma unroll
    for (int k = 0; k < 8; ++k) r[k] = __fmul_rn(x[k], x[k]);
#pragma unroll
    for (int i = 8; i < DIM; i += 8)
#pragma unroll
        for (int k = 0; k < 8; ++k)
            r[k] = __fadd_rn(r[k], __fmul_rn(x[i + k], x[i + k]));
    const float ff = __fadd_rn(
        __fadd_rn(__fadd_rn(r[0], r[1]), __fadd_rn(r[2], r[3])),
        __fadd_rn(__fadd_rn(r[4], r[5]), __fadd_rn(r[6], r[7])));

    float minv = __builtin_inff();
    int   mini = 0;
    const int jbase = blockIdx.y * CPS;   // block-uniform

#pragma unroll 1
    for (int jj = 0; jj < CPS; jj += 4) {
        const int j0 = jbase + jj;
        const float* e = eT + (size_t)j0 * DIM;   // block-uniform -> s_load
        float a0 = 0.f, a1 = 0.f, a2 = 0.f, a3 = 0.f;
#pragma unroll
        for (int d = 0; d < DIM; ++d) {
            const float xd = x[d];
            a0 = fmaf(xd, e[d],           a0);
            a1 = fmaf(xd, e[DIM + d],     a1);
            a2 = fmaf(xd, e[2 * DIM + d], a2);
            a3 = fmaf(xd, e[3 * DIM + d], a3);
        }
        const float d0 = __fadd_rn(__fsub_rn(ff, __fmul_rn(2.f, a0)), cn[j0 + 0]);
        const float d1 = __fadd_rn(__fsub_rn(ff, __fmul_rn(2.f, a1)), cn[j0 + 1]);
        const float d2 = __fadd_rn(__fsub_rn(ff, __fmul_rn(2.f, a2)), cn[j0 + 2]);
        const float d3 = __fadd_rn(__fsub_rn(ff, __fmul_rn(2.f, a3)), cn[j0 + 3]);
        if (d0 < minv) { minv = d0; mini = j0 + 0; }
        if (d1 < minv) { minv = d1; mini = j0 + 1; }
        if (d2 < minv) { minv = d2; mini = j0 + 2; }
        if (d3 < minv) { minv = d3; mini = j0 + 3; }
    }

    cand[(size_t)blockIdx.y * NPIX + pix] =
        ((unsigned long long)__float_as_uint(minv) << 32) | (unsigned)mini;
}

// ---------------------------------------------------------------------------
// finish: merge NSPLIT candidates per pixel, gather code, write q_out =
// x + (q - x), accumulate MSE loss.
// ---------------------------------------------------------------------------
__global__ __launch_bounds__(256) void finish_kernel(const float* __restrict__ X,
                                                     const float* __restrict__ embed,
                                                     const unsigned long long* __restrict__ cand,
                                                     float* __restrict__ OUT,
                                                     float* __restrict__ loss) {
    const int tid = threadIdx.x;
    const int pix = blockIdx.x * 256 + tid;
    const int b   = pix >> 12;
    const int p   = pix & 4095;

    unsigned long long m = cand[pix];
#pragma unroll
    for (int s = 1; s < NSPLIT; ++s) {
        const unsigned long long c = cand[(size_t)s * NPIX + pix];
        m = (c < m) ? c : m;
    }
    const int idx = (int)(m & 0xFFFFFFFFull);

    const float* xb  = X   + (size_t)b * (DIM * HW) + p;
    float*      outb = OUT + (size_t)b * (DIM * HW) + p;
    float lerr = 0.f;
#pragma unroll
    for (int d = 0; d < DIM; ++d) {
        const float qv = embed[d * NEMB + idx];   // 256 KB, L2-resident gather
        const float xv = xb[(size_t)d * HW];
        const float df = __fsub_rn(qv, xv);
        outb[(size_t)d * HW] = __fadd_rn(xv, df); // coalesced across lanes
        lerr = fmaf(df, df, lerr);
    }

    __shared__ float sred[256];
    sred[tid] = lerr;
    __syncthreads();
#pragma unroll
    for (int s = 128; s > 0; s >>= 1) {
        if (tid < s) sred[tid] += sred[tid + s];
        __syncthreads();
    }
    if (tid == 0)
        atomicAdd(loss, sred[0] * (1.0f / (float)NOUT));
}

// ---------------------------------------------------------------------------
// fallback (ws too small for candidates): fused R0 structure with the
// spill fix. Same arithmetic, full 1024-code block-uniform scan.
// ---------------------------------------------------------------------------
__global__ __launch_bounds__(256, 3) void vq_full(const float* __restrict__ X,
                                                  const float* __restrict__ embed,
                                                  const float* __restrict__ eT,
                                                  const float* __restrict__ cn,
                                                  float* __restrict__ OUT,
                                                  float* __restrict__ loss) {
    const int tid = threadIdx.x;
    const int pix = blockIdx.x * 256 + tid;
    const int b   = pix >> 12;
    const int p   = pix & 4095;
    const float* xb = X + (size_t)b * (DIM * HW) + p;

    float x[DIM];
#pragma unroll
    for (int d = 0; d < DIM; ++d) x[d] = xb[(size_t)d * HW];

    float r[8];
#pragma unroll
    for (int k = 0; k < 8; ++k) r[k] = __fmul_rn(x[k], x[k]);
#pragma unroll
    for (int i = 8; i < DIM; i += 8)
#pragma unroll
        for (int k = 0; k < 8; ++k)
            r[k] = __fadd_rn(r[k], __fmul_rn(x[i + k], x[i + k]));
    const float ff = __fadd_rn(
        __fadd_rn(__fadd_rn(r[0], r[1]), __fadd_rn(r[2], r[3])),
        __fadd_rn(__fadd_rn(r[4], r[5]), __fadd_rn(r[6], r[7])));

    float minv = __builtin_inff();
    int   mini = 0;
#pragma unroll 1
    for (int j0 = 0; j0 < NEMB; j0 += 4) {
        const float* e = eT + (size_t)j0 * DIM;
        float a0 = 0.f, a1 = 0.f, a2 = 0.f, a3 = 0.f;
#pragma unroll
        for (int d = 0; d < DIM; ++d) {
            const float xd = x[d];
            a0 = fmaf(xd, e[d],           a0);
            a1 = fmaf(xd, e[DIM + d],     a1);
            a2 = fmaf(xd, e[2 * DIM + d], a2);
            a3 = fmaf(xd, e[3 * DIM + d], a3);
        }
        const float d0 = __fadd_rn(__fsub_rn(ff, __fmul_rn(2.f, a0)), cn[j0 + 0]);
        const float d1 = __fadd_rn(__fsub_rn(ff, __fmul_rn(2.f, a1)), cn[j0 + 1]);
        const float d2 = __fadd_rn(__fsub_rn(ff, __fmul_rn(2.f, a2)), cn[j0 + 2]);
        const float d3 = __fadd_rn(__fsub_rn(ff, __fmul_rn(2.f, a3)), cn[j0 + 3]);
        if (d0 < minv) { minv = d0; mini = j0 + 0; }
        if (d1 < minv) { minv = d1; mini = j0 + 1; }
        if (d2 < minv) { minv = d2; mini = j0 + 2; }
        if (d3 < minv) { minv = d3; mini = j0 + 3; }
    }

    float lerr = 0.f;
    float* outb = OUT + (size_t)b * (DIM * HW) + p;
#pragma unroll
    for (int d = 0; d < DIM; ++d) {
        const float qv = embed[d * NEMB + mini];
        const float df = __fsub_rn(qv, x[d]);
        outb[(size_t)d * HW] = __fadd_rn(x[d], df);
        lerr = fmaf(df, df, lerr);
    }

    __shared__ float sred[256];
    sred[tid] = lerr;
    __syncthreads();
#pragma unroll
    for (int s = 128; s > 0; s >>= 1) {
        if (tid < s) sred[tid] += sred[tid + s];
        __syncthreads();
    }
    if (tid == 0)
        atomicAdd(loss, sred[0] * (1.0f / (float)NOUT));
}

extern "C" void kernel_launch(void* const* d_in, const int* in_sizes, int n_in,
                              void* d_out, int out_size, void* d_ws, size_t ws_size,
                              hipStream_t stream) {
    const float* X = (const float*)d_in[0];
    const float* E = (const float*)d_in[1];
    float* OUT  = (float*)d_out;
    float* loss = OUT + NOUT;

    // ws layout: [cand: NSPLIT*NPIX u64][eT: 1024*64 f32][cn: 1024 f32]
    const size_t cand_bytes = (size_t)NSPLIT * NPIX * 8;
    const size_t need = cand_bytes + (size_t)(NEMB * DIM + NEMB) * 4;

    hipMemsetAsync(loss, 0, sizeof(float), stream);

    if (ws_size >= need) {
        unsigned long long* cand = (unsigned long long*)d_ws;
        float* eT = (float*)((char*)d_ws + cand_bytes);
        float* cn = eT + NEMB * DIM;
        prep_kernel<<<NEMB / 256, 256, 0, stream>>>(E, eT, cn);
        scan_kernel<<<dim3(NPIX / 256, NSPLIT), 256, 0, stream>>>(X, eT, cn, cand);
        finish_kernel<<<NPIX / 256, 256, 0, stream>>>(X, E, cand, OUT, loss);
    } else {
        float* eT = (float*)d_ws;
        float* cn = eT + NEMB * DIM;
        prep_kernel<<<NEMB / 256, 256, 0, stream>>>(E, eT, cn);
        vq_full<<<NPIX / 256, 256, 0, stream>>>(X, E, eT, cn, OUT, loss);
    }
}